// Round 6
// baseline (291.864 us; speedup 1.0000x reference)
//
#include <hip/hip_runtime.h>
#include <hip/hip_bf16.h>

typedef __attribute__((ext_vector_type(8))) short short8;
typedef __attribute__((ext_vector_type(4))) float f32x4;

__device__ __forceinline__ short8 load_af(const unsigned short* p) {
  union { uint2 u[2]; short8 v; } r;
  r.u[0] = *(const uint2*)(p);        // k = k0..k0+3
  r.u[1] = *(const uint2*)(p + 16);   // k = k0+16..k0+19
  return r.v;
}

__device__ __forceinline__ unsigned int pk_bf16(float a, float b) {
  __hip_bfloat162 h = __float22bfloat162_rn(make_float2(a, b));
  return *(unsigned int*)&h;
}
__device__ __forceinline__ unsigned short s_bf16(float a) {
  __hip_bfloat16 h = __float2bfloat16(a);
  return *(unsigned short*)&h;
}

// cvt two float4 (k0..3, k16..19) -> short8 A-frag
__device__ __forceinline__ short8 cvt_af(const float4& lo, const float4& hi) {
  union { uint4 u; short8 v; } r;
  r.u.x = pk_bf16(lo.x, lo.y);
  r.u.y = pk_bf16(lo.z, lo.w);
  r.u.z = pk_bf16(hi.x, hi.y);
  r.u.w = pk_bf16(hi.z, hi.w);
  return r.v;
}

// ---------------------------------------------------------------------------
// prep (fused): build all MFMA B-fragments directly (verified r3/r4, absmax ok).
// ---------------------------------------------------------------------------
__global__ __launch_bounds__(256) void prep_kernel(
    const float* __restrict__ W1, const float* __restrict__ W2,
    const float* __restrict__ W3,
    unsigned short* __restrict__ fL1, unsigned short* __restrict__ fL2,
    unsigned short* __restrict__ fL3) {
  const int w = blockIdx.x * 4 + (threadIdx.x >> 6);
  const int lane = threadIdx.x & 63;
  const int rlo = lane & 15;
  const int q4 = (lane >> 4) << 2;

  if (w < 512) {
    const int nt = w >> 5, kk = w & 31;
    const int col = nt * 16 + rlo;
    const int k0 = kk * 32 + q4;
    float pc[8], ps[8], dc[8], dsn[8], acc[8];
#pragma unroll
    for (int e = 0; e < 8; ++e) {
      int ke = k0 + (e & 3) + ((e >> 2) << 4);
      float ang = (float)ke * 6.135923151542565e-3f;  // 2*pi/1024
      float s, c;
      __sincosf(ang, &s, &c);
      dc[e] = c; dsn[e] = s;
      pc[e] = 1.f; ps[e] = 0.f;
      acc[e] = 0.f;
    }
    const float* pw = W1 + col;
#pragma unroll 2
    for (int m = 0; m < 192; ++m) {
      float wre = pw[0];     // W1[2m][col]
      float wio = pw[256];   // W1[2m+1][col]
      pw += 512;
#pragma unroll
      for (int e = 0; e < 8; ++e) {
        acc[e] = fmaf(pc[e], wre, acc[e]);
        acc[e] = fmaf(-ps[e], wio, acc[e]);
        float c2 = pc[e] * dc[e] - ps[e] * dsn[e];
        float s2 = ps[e] * dc[e] + pc[e] * dsn[e];
        pc[e] = c2; ps[e] = s2;
      }
    }
    uint4 v;
    v.x = pk_bf16(acc[0], acc[1]);
    v.y = pk_bf16(acc[2], acc[3]);
    v.z = pk_bf16(acc[4], acc[5]);
    v.w = pk_bf16(acc[6], acc[7]);
    *(uint4*)(fL1 + ((size_t)w * 64 + lane) * 8) = v;
  } else if (w < 576) {
    const int tl = w - 512;
    const int nt = tl >> 3, kk = tl & 7;
    const int col = nt * 16 + rlo;
    const int k0 = kk * 32 + q4;
    float a[8];
#pragma unroll
    for (int e = 0; e < 8; ++e) {
      int ke = k0 + (e & 3) + ((e >> 2) << 4);
      a[e] = W2[ke * 128 + col];
    }
    uint4 v;
    v.x = pk_bf16(a[0], a[1]); v.y = pk_bf16(a[2], a[3]);
    v.z = pk_bf16(a[4], a[5]); v.w = pk_bf16(a[6], a[7]);
    *(uint4*)(fL2 + ((size_t)tl * 64 + lane) * 8) = v;
  } else {
    const int tl = w - 576;
    const int nt = tl >> 2, kk = tl & 3;
    const int col = nt * 16 + rlo;
    const int k0 = kk * 32 + q4;
    float a[8];
#pragma unroll
    for (int e = 0; e < 8; ++e) {
      int ke = k0 + (e & 3) + ((e >> 2) << 4);
      a[e] = W3[ke * 32 + col];
    }
    uint4 v;
    v.x = pk_bf16(a[0], a[1]); v.y = pk_bf16(a[2], a[3]);
    v.z = pk_bf16(a[4], a[5]); v.w = pk_bf16(a[6], a[7]);
    *(uint4*)(fL3 + ((size_t)tl * 64 + lane) * 8) = v;
  }
}

// ---------------------------------------------------------------------------
// fused MLP. 512 blocks x 256 thr (4 waves), BM=64.
// Phase 1 (K=1024 GEMM): NO LDS, NO barriers. Each wave streams its A-frags
// directly from global x (two float4 per m-tile per K-step; 64B-sector
// perfect). 4 waves of a block read the same x panel ~in lockstep -> L2
// dedups. A and B prefetched 1 K-step ahead under counted vmcnt; waves slip
// freely -> deep HBM pipeline.
// Phases 2/3: h1/h2 exchanged via LDS (2 barriers total).
// ---------------------------------------------------------------------------
#define H1_S 260   // ushorts (520 B row stride)
#define H2_S 132

__global__ __launch_bounds__(256, 2) void mlp_kernel(
    const float* __restrict__ x,
    const float* __restrict__ b1, const float* __restrict__ b2,
    const float* __restrict__ b3,
    const unsigned short* __restrict__ fL1, const unsigned short* __restrict__ fL2,
    const unsigned short* __restrict__ fL3, float* __restrict__ out) {
  __shared__ unsigned short h1s[64 * H1_S];
  __shared__ unsigned short h2s[64 * H2_S];
  const int t = threadIdx.x;
  const int lane = t & 63;
  const int wid = t >> 6;
  const int rlo = lane & 15;
  const int g4 = (lane >> 4) << 2;
  const size_t row0 = (size_t)blockIdx.x * 64;

  // per-lane base: row = row0 + rlo (+ m*16), col offset g4
  const float* xb = x + (row0 + rlo) * 1024 + g4;
  const unsigned short* fb = fL1 + ((size_t)wid * 4 * 32 * 64 + lane) * 8;

  f32x4 acc[4][4] = {};

  // ---- phase 1: K-loop of 32 steps, fully barrier-free
  float4 ac[4][2], an[4][2];
  short8 bc[4], bn[4];
#pragma unroll
  for (int m = 0; m < 4; ++m) {
    ac[m][0] = *(const float4*)(xb + m * 16384);
    ac[m][1] = *(const float4*)(xb + m * 16384 + 16);
  }
#pragma unroll
  for (int c = 0; c < 4; ++c)
    bc[c] = *(const short8*)(fb + (size_t)c * 32 * 512);

#pragma unroll 2
  for (int kk = 0; kk < 32; ++kk) {
    if (kk < 31) {
#pragma unroll
      for (int m = 0; m < 4; ++m) {
        an[m][0] = *(const float4*)(xb + m * 16384 + (kk + 1) * 32);
        an[m][1] = *(const float4*)(xb + m * 16384 + (kk + 1) * 32 + 16);
      }
#pragma unroll
      for (int c = 0; c < 4; ++c)
        bn[c] = *(const short8*)(fb + ((size_t)c * 32 + kk + 1) * 512);
    }
    short8 af[4];
#pragma unroll
    for (int m = 0; m < 4; ++m) af[m] = cvt_af(ac[m][0], ac[m][1]);
#pragma unroll
    for (int m = 0; m < 4; ++m)
#pragma unroll
      for (int c = 0; c < 4; ++c)
        acc[m][c] = __builtin_amdgcn_mfma_f32_16x16x32_bf16(af[m], bc[c], acc[m][c], 0, 0, 0);
    if (kk < 31) {
#pragma unroll
      for (int m = 0; m < 4; ++m) { ac[m][0] = an[m][0]; ac[m][1] = an[m][1]; }
#pragma unroll
      for (int c = 0; c < 4; ++c) bc[c] = bn[c];
    }
  }

  // ---- L1 epilogue: bias + leaky -> h1 (bf16 in LDS)
  {
    float bv[4];
#pragma unroll
    for (int c = 0; c < 4; ++c) bv[c] = b1[wid * 64 + c * 16 + rlo];
#pragma unroll
    for (int m = 0; m < 4; ++m)
#pragma unroll
      for (int c = 0; c < 4; ++c)
#pragma unroll
        for (int r = 0; r < 4; ++r) {
          float v = acc[m][c][r] + bv[c];
          v = fmaxf(v, 0.01f * v);
          h1s[(m * 16 + g4 + r) * H1_S + wid * 64 + c * 16 + rlo] = s_bf16(v);
        }
  }
  __syncthreads();

  // ---- L2: 64 rows x 32 cols per wave, K = 256
  f32x4 a2[4][2] = {};
#pragma unroll
  for (int ks = 0; ks < 8; ++ks) {
    short8 af[4];
#pragma unroll
    for (int m = 0; m < 4; ++m)
      af[m] = load_af(h1s + (m * 16 + rlo) * H1_S + ks * 32 + g4);
    short8 bfr[2];
#pragma unroll
    for (int c = 0; c < 2; ++c)
      bfr[c] = *(const short8*)(fL2 + (((size_t)(wid * 2 + c) * 8 + ks) * 64 + lane) * 8);
#pragma unroll
    for (int m = 0; m < 4; ++m)
#pragma unroll
      for (int c = 0; c < 2; ++c)
        a2[m][c] = __builtin_amdgcn_mfma_f32_16x16x32_bf16(af[m], bfr[c], a2[m][c], 0, 0, 0);
  }
  {
    float bv[2];
#pragma unroll
    for (int c = 0; c < 2; ++c) bv[c] = b2[wid * 32 + c * 16 + rlo];
#pragma unroll
    for (int m = 0; m < 4; ++m)
#pragma unroll
      for (int c = 0; c < 2; ++c)
#pragma unroll
        for (int r = 0; r < 4; ++r) {
          float v = a2[m][c][r] + bv[c];
          v = fmaxf(v, 0.01f * v);
          h2s[(m * 16 + g4 + r) * H2_S + wid * 32 + c * 16 + rlo] = s_bf16(v);
        }
  }
  __syncthreads();

  // ---- L3: rowtile = wid (16 rows) x 32 cols, K = 128, no activation
  f32x4 a3[2] = {};
#pragma unroll
  for (int ks = 0; ks < 4; ++ks) {
    short8 af = load_af(h2s + (wid * 16 + rlo) * H2_S + ks * 32 + g4);
#pragma unroll
    for (int c = 0; c < 2; ++c) {
      short8 bfr = *(const short8*)(fL3 + (((size_t)c * 4 + ks) * 64 + lane) * 8);
      a3[c] = __builtin_amdgcn_mfma_f32_16x16x32_bf16(af, bfr, a3[c], 0, 0, 0);
    }
  }
  {
    float bv[2];
    bv[0] = b3[rlo];
    bv[1] = b3[16 + rlo];
#pragma unroll
    for (int c = 0; c < 2; ++c)
#pragma unroll
      for (int r = 0; r < 4; ++r)
        out[(row0 + wid * 16 + g4 + r) * 32 + c * 16 + rlo] = a3[c][r] + bv[c];
  }
}

// ---------------------------------------------------------------------------
extern "C" void kernel_launch(void* const* d_in, const int* in_sizes, int n_in,
                              void* d_out, int out_size, void* d_ws, size_t ws_size,
                              hipStream_t stream) {
  const float* x  = (const float*)d_in[0];
  const float* W1 = (const float*)d_in[1];
  const float* b1 = (const float*)d_in[2];
  const float* W2 = (const float*)d_in[3];
  const float* b2 = (const float*)d_in[4];
  const float* W3 = (const float*)d_in[5];
  const float* b3 = (const float*)d_in[6];
  float* out = (float*)d_out;

  char* ws = (char*)d_ws;
  unsigned short* fL1 = (unsigned short*)ws;                 // 512 KiB
  unsigned short* fL2 = (unsigned short*)(ws + 524288);      //  64 KiB
  unsigned short* fL3 = (unsigned short*)(ws + 589824);      //   8 KiB

  hipLaunchKernelGGL(prep_kernel, dim3(146), dim3(256), 0, stream,
                     W1, W2, W3, fL1, fL2, fL3);
  hipLaunchKernelGGL(mlp_kernel, dim3(512), dim3(256), 0, stream,
                     x, b1, b2, b3, fL1, fL2, fL3, out);
}